// Round 1
// baseline (525.462 us; speedup 1.0000x reference)
//
#include <hip/hip_runtime.h>
#include <hip/hip_bf16.h>

#define BB 32
#define SS 2048
#define DD 1024
#define UU 1024
#define MBLK 64

typedef short bf16x8 __attribute__((ext_vector_type(8)));
typedef float f32x4 __attribute__((ext_vector_type(4)));

__device__ __forceinline__ unsigned short f2bf(float x) {
    union { float f; unsigned int u; } v; v.f = x;
    unsigned int r = v.u + 0x7fffu + ((v.u >> 16) & 1u);
    return (unsigned short)(r >> 16);
}

// ---------------- K1a: q_proj = query@w1 + b1 + b2 ----------------
__global__ void qproj_kernel(const float* __restrict__ query, const float* __restrict__ w1,
                             const float* __restrict__ b1, const float* __restrict__ b2,
                             float* __restrict__ qp2) {
    __shared__ float qs[DD];
    const int b = blockIdx.x;   // 32
    const int uc = blockIdx.y;  // 4
    const int t = threadIdx.x;  // 256
    for (int i = t; i < DD; i += 256) qs[i] = query[b * DD + i];
    __syncthreads();
    const int u = uc * 256 + t;
    float acc = 0.f;
#pragma unroll 4
    for (int d = 0; d < DD; ++d) acc = fmaf(qs[d], w1[d * UU + u], acc);
    qp2[b * UU + u] = acc + b1[u] + b2[u];
}

// ---------------- K1b: w2t[u][d] = bf16(w2[d][u]) ----------------
__global__ void w2t_kernel(const float* __restrict__ w2, unsigned short* __restrict__ w2t) {
    __shared__ float tile[64][65];
    const int u0 = blockIdx.x * 64;
    const int d0 = blockIdx.y * 64;
    const int t = threadIdx.x;
    const int c = t & 63, rg = t >> 6;
#pragma unroll
    for (int rr = 0; rr < 16; ++rr) {
        int dl = rg * 16 + rr;
        tile[dl][c] = w2[(size_t)(d0 + dl) * UU + u0 + c];
    }
    __syncthreads();
#pragma unroll
    for (int rr = 0; rr < 16; ++rr) {
        int ul = rg * 16 + rr;
        w2t[(size_t)(u0 + ul) * DD + d0 + c] = f2bf(tile[c][ul]);
    }
}

// ---------------- K2: fused GEMM + tanh + wv-reduce -> score[b,s] ----------------
__global__ __launch_bounds__(256, 1)
void score_kernel(const float* __restrict__ values, const unsigned short* __restrict__ w2t,
                  const float* __restrict__ qp2, const float* __restrict__ wv,
                  const float* __restrict__ bv, float* __restrict__ score) {
    __shared__ __align__(16) unsigned short Vs[MBLK * DD];  // 128 KB, XOR-swizzled
    __shared__ float ssum[4][MBLK];

    const int blk = blockIdx.x;       // 1024
    const int b = blk >> 5;           // 32 tiles of 64 rows per batch
    const int s0 = (blk & 31) * MBLK;
    const int tid = threadIdx.x;
    const int lane = tid & 63;
    const int wid = tid >> 6;

    // stage V tile: f32 -> bf16, swizzled
    const float* vbase = values + ((size_t)b * SS + s0) * DD;
    {
        const int dt = tid * 4;  // 0..1020
#pragma unroll 4
        for (int row = 0; row < MBLK; ++row) {
            float4 v = *reinterpret_cast<const float4*>(vbase + (size_t)row * DD + dt);
            unsigned short h0 = f2bf(v.x), h1 = f2bf(v.y), h2 = f2bf(v.z), h3 = f2bf(v.w);
            int idx = row * DD + (dt ^ ((row & 7) << 3));
            ushort4 pack; pack.x = h0; pack.y = h1; pack.z = h2; pack.w = h3;
            *reinterpret_cast<ushort4*>(&Vs[idx]) = pack;
        }
    }
    __syncthreads();

    const int arow = lane & 15;        // frag row (A) / frag col (B,D)
    const int kgrp = (lane >> 4) * 8;  // k offset within frag

    float rowsum[16];
#pragma unroll
    for (int i = 0; i < 16; ++i) rowsum[i] = 0.f;

    for (int p = 0; p < 4; ++p) {
        const int nb = (p * 4 + wid) * 64;  // this wave's 64-col slice
        f32x4 acc[4][4];
#pragma unroll
        for (int mf = 0; mf < 4; ++mf)
#pragma unroll
            for (int nf = 0; nf < 4; ++nf) { f32x4 z = {0.f, 0.f, 0.f, 0.f}; acc[mf][nf] = z; }

        const unsigned short* wbase = w2t + (size_t)(nb + arow) * DD + kgrp;

#pragma unroll 2
        for (int kk = 0; kk < DD / 32; ++kk) {
            const int k = kk * 32 + kgrp;
            bf16x8 a[4], bf[4];
#pragma unroll
            for (int mf = 0; mf < 4; ++mf) {
                int row = mf * 16 + arow;
                a[mf] = *reinterpret_cast<const bf16x8*>(&Vs[row * DD + (k ^ ((row & 7) << 3))]);
            }
#pragma unroll
            for (int nf = 0; nf < 4; ++nf)
                bf[nf] = *reinterpret_cast<const bf16x8*>(wbase + (size_t)nf * 16 * DD + kk * 32);
#pragma unroll
            for (int mf = 0; mf < 4; ++mf)
#pragma unroll
                for (int nf = 0; nf < 4; ++nf)
                    acc[mf][nf] = __builtin_amdgcn_mfma_f32_16x16x32_bf16(a[mf], bf[nf], acc[mf][nf], 0, 0, 0);
        }

        // epilogue: tanh + wv weighting, accumulate per-row partials
#pragma unroll
        for (int nf = 0; nf < 4; ++nf) {
            const int u = nb + nf * 16 + arow;  // D-layout: col = lane&15
            const float qv = qp2[b * UU + u];
            const float wvv = wv[u];
#pragma unroll
            for (int mf = 0; mf < 4; ++mf)
#pragma unroll
                for (int i = 0; i < 4; ++i) {
                    float h = acc[mf][nf][i] + qv;
                    float e = __expf(2.f * h);
                    float th = 1.f - 2.f / (e + 1.f);
                    rowsum[mf * 4 + i] = fmaf(th, wvv, rowsum[mf * 4 + i]);
                }
        }
    }

    // reduce across the 16 lanes holding different cols of the same rows
#pragma unroll
    for (int i = 0; i < 16; ++i) {
        float v = rowsum[i];
        v += __shfl_xor(v, 1);
        v += __shfl_xor(v, 2);
        v += __shfl_xor(v, 4);
        v += __shfl_xor(v, 8);
        rowsum[i] = v;
    }
    if ((lane & 15) == 0) {
        const int rg = lane >> 4;  // row-group 0..3
#pragma unroll
        for (int mf = 0; mf < 4; ++mf)
#pragma unroll
            for (int i = 0; i < 4; ++i)
                ssum[wid][mf * 16 + rg * 4 + i] = rowsum[mf * 4 + i];
    }
    __syncthreads();
    if (tid < MBLK) {
        float sc = ssum[0][tid] + ssum[1][tid] + ssum[2][tid] + ssum[3][tid] + bv[0];
        score[b * SS + s0 + tid] = sc;
    }
}

// ---------------- K3a: softmax over S per batch ----------------
__global__ void softmax_kernel(const float* __restrict__ score, float* __restrict__ weights) {
    __shared__ float red[8];
    const int b = blockIdx.x;
    const int t = threadIdx.x;  // 256
    float local[8];
    float mx = -1e30f;
#pragma unroll
    for (int i = 0; i < 8; ++i) {
        local[i] = score[b * SS + i * 256 + t];
        mx = fmaxf(mx, local[i]);
    }
    for (int off = 1; off < 64; off <<= 1) mx = fmaxf(mx, __shfl_xor(mx, off));
    if ((t & 63) == 0) red[t >> 6] = mx;
    __syncthreads();
    const float m = fmaxf(fmaxf(red[0], red[1]), fmaxf(red[2], red[3]));
    float sum = 0.f;
#pragma unroll
    for (int i = 0; i < 8; ++i) {
        local[i] = __expf(local[i] - m);
        sum += local[i];
    }
    for (int off = 1; off < 64; off <<= 1) sum += __shfl_xor(sum, off);
    if ((t & 63) == 0) red[4 + (t >> 6)] = sum;
    __syncthreads();
    const float inv = 1.f / (red[4] + red[5] + red[6] + red[7]);
#pragma unroll
    for (int i = 0; i < 8; ++i) weights[b * SS + i * 256 + t] = local[i] * inv;
}

// ---------------- K3b: context[b,d] = sum_s w[b,s] * values[b,s,d] ----------------
__global__ void context_kernel(const float* __restrict__ values, const float* __restrict__ weights,
                               float* __restrict__ ctx) {
    __shared__ float part[128];
    const int b = blockIdx.x;   // 32
    const int dc = blockIdx.y;  // 8
    const int t = threadIdx.x;  // 256
    const int d = dc * 128 + (t & 127);
    const int sh = t >> 7;  // 0 or 1
    const float* vb = values + (size_t)b * SS * DD + d;
    float acc = 0.f;
#pragma unroll 8
    for (int s = sh; s < SS; s += 2)
        acc = fmaf(weights[b * SS + s], vb[(size_t)s * DD], acc);
    if (sh) part[t & 127] = acc;
    __syncthreads();
    if (!sh) ctx[b * DD + d] = acc + part[t & 127];
}

extern "C" void kernel_launch(void* const* d_in, const int* in_sizes, int n_in,
                              void* d_out, int out_size, void* d_ws, size_t ws_size,
                              hipStream_t stream) {
    const float* query  = (const float*)d_in[0];
    const float* values = (const float*)d_in[1];
    const float* w1     = (const float*)d_in[2];
    const float* b1     = (const float*)d_in[3];
    const float* w2     = (const float*)d_in[4];
    const float* b2     = (const float*)d_in[5];
    const float* wv     = (const float*)d_in[6];
    const float* bv     = (const float*)d_in[7];

    float* ctx     = (float*)d_out;                    // [B, D]
    float* weights = (float*)d_out + (size_t)BB * DD;  // [B, S, 1]

    float* qp2           = (float*)d_ws;                                  // 128 KB
    unsigned short* w2t  = (unsigned short*)((char*)d_ws + 131072);       // 2 MB
    float* score         = (float*)((char*)d_ws + 131072 + 2097152);      // 256 KB

    qproj_kernel<<<dim3(BB, UU / 256), 256, 0, stream>>>(query, w1, b1, b2, qp2);
    w2t_kernel<<<dim3(UU / 64, DD / 64), 256, 0, stream>>>(w2, w2t);
    score_kernel<<<dim3(BB * SS / MBLK), 256, 0, stream>>>(values, w2t, qp2, wv, bv, score);
    softmax_kernel<<<dim3(BB), 256, 0, stream>>>(score, weights);
    context_kernel<<<dim3(BB, 8), 256, 0, stream>>>(values, weights, ctx);
}

// Round 2
// 465.944 us; speedup vs baseline: 1.1277x; 1.1277x over previous
//
#include <hip/hip_runtime.h>
#include <hip/hip_bf16.h>

#define BB 32
#define SS 2048
#define DD 1024
#define UU 1024
#define MBLK 64

typedef short bf16x8 __attribute__((ext_vector_type(8)));
typedef float f32x4 __attribute__((ext_vector_type(4)));

__device__ __forceinline__ unsigned short f2bf(float x) {
    union { float f; unsigned int u; } v; v.f = x;
    unsigned int r = v.u + 0x7fffu + ((v.u >> 16) & 1u);
    return (unsigned short)(r >> 16);
}

// ---------------- K1a: q_proj = query@w1 + b1 + b2 ----------------
__global__ void qproj_kernel(const float* __restrict__ query, const float* __restrict__ w1,
                             const float* __restrict__ b1, const float* __restrict__ b2,
                             float* __restrict__ qp2) {
    __shared__ float qs[DD];
    const int b = blockIdx.x;   // 32
    const int uc = blockIdx.y;  // 4
    const int t = threadIdx.x;  // 256
    for (int i = t; i < DD; i += 256) qs[i] = query[b * DD + i];
    __syncthreads();
    const int u = uc * 256 + t;
    float acc = 0.f;
#pragma unroll 4
    for (int d = 0; d < DD; ++d) acc = fmaf(qs[d], w1[d * UU + u], acc);
    qp2[b * UU + u] = acc + b1[u] + b2[u];
}

// ---------------- K1b: w2t[u][d] = bf16(w2[d][u]) ----------------
__global__ void w2t_kernel(const float* __restrict__ w2, unsigned short* __restrict__ w2t) {
    __shared__ float tile[64][65];
    const int u0 = blockIdx.x * 64;
    const int d0 = blockIdx.y * 64;
    const int t = threadIdx.x;
    const int c = t & 63, rg = t >> 6;
#pragma unroll
    for (int rr = 0; rr < 16; ++rr) {
        int dl = rg * 16 + rr;
        tile[dl][c] = w2[(size_t)(d0 + dl) * UU + u0 + c];
    }
    __syncthreads();
#pragma unroll
    for (int rr = 0; rr < 16; ++rr) {
        int ul = rg * 16 + rr;
        w2t[(size_t)(u0 + ul) * DD + d0 + c] = f2bf(tile[c][ul]);
    }
}

// ---------------- K2: fused GEMM + tanh + wv-reduce -> score[b,s] ----------------
// 512 threads = 8 waves (2/SIMD). Each wave owns a 64-col U-slice per pass, 2 passes.
__global__ __launch_bounds__(512, 2)
void score_kernel(const float* __restrict__ values, const unsigned short* __restrict__ w2t,
                  const float* __restrict__ qp2, const float* __restrict__ wv,
                  const float* __restrict__ bv, float* __restrict__ score) {
    __shared__ __align__(16) unsigned short Vs[MBLK * DD];  // 128 KB, XOR-swizzled
    __shared__ float ssum[8][MBLK];

    const int blk = blockIdx.x;       // 1024
    const int b = blk >> 5;           // 32 tiles of 64 rows per batch
    const int s0 = (blk & 31) * MBLK;
    const int tid = threadIdx.x;
    const int lane = tid & 63;
    const int wid = tid >> 6;

    // ---- stage V tile: f32 -> bf16, swizzled. 512 thr x 8 elems x 16 iters = 64x1024
    {
        const int rsub = tid >> 7;       // row-within-4
        const int col8 = tid & 127;      // 8-elem chunk index
        const float* vb = values + ((size_t)b * SS + s0) * DD;
#pragma unroll 4
        for (int it = 0; it < 16; ++it) {
            const int row = it * 4 + rsub;
            const float* src = vb + (size_t)row * DD + col8 * 8;
            float4 x = *reinterpret_cast<const float4*>(src);
            float4 y = *reinterpret_cast<const float4*>(src + 4);
            bf16x8 pk;
            pk[0] = (short)f2bf(x.x); pk[1] = (short)f2bf(x.y);
            pk[2] = (short)f2bf(x.z); pk[3] = (short)f2bf(x.w);
            pk[4] = (short)f2bf(y.x); pk[5] = (short)f2bf(y.y);
            pk[6] = (short)f2bf(y.z); pk[7] = (short)f2bf(y.w);
            const int eidx = (col8 * 8) ^ ((row & 7) << 3);  // element-index XOR swizzle
            *reinterpret_cast<bf16x8*>(&Vs[row * DD + eidx]) = pk;
        }
    }
    __syncthreads();

    const int arow = lane & 15;        // frag row (A) / frag col (B,D)
    const int kgrp = (lane >> 4) * 8;  // k offset within frag

    float rowsum[16];
#pragma unroll
    for (int i = 0; i < 16; ++i) rowsum[i] = 0.f;

#pragma unroll 1
    for (int p = 0; p < 2; ++p) {
        const int nb = (p * 8 + wid) * 64;  // this wave's 64-col slice
        f32x4 acc[4][4];
#pragma unroll
        for (int mf = 0; mf < 4; ++mf)
#pragma unroll
            for (int nf = 0; nf < 4; ++nf) { f32x4 z = {0.f, 0.f, 0.f, 0.f}; acc[mf][nf] = z; }

        const unsigned short* wbase = w2t + (size_t)(nb + arow) * DD + kgrp;

#pragma unroll 4
        for (int kk = 0; kk < DD / 32; ++kk) {
            const int k = kk * 32 + kgrp;
            bf16x8 a[4], bf[4];
#pragma unroll
            for (int nf = 0; nf < 4; ++nf)
                bf[nf] = *reinterpret_cast<const bf16x8*>(wbase + (size_t)nf * 16 * DD + kk * 32);
#pragma unroll
            for (int mf = 0; mf < 4; ++mf) {
                int row = mf * 16 + arow;
                a[mf] = *reinterpret_cast<const bf16x8*>(&Vs[row * DD + (k ^ ((row & 7) << 3))]);
            }
#pragma unroll
            for (int mf = 0; mf < 4; ++mf)
#pragma unroll
                for (int nf = 0; nf < 4; ++nf)
                    acc[mf][nf] = __builtin_amdgcn_mfma_f32_16x16x32_bf16(a[mf], bf[nf], acc[mf][nf], 0, 0, 0);
        }

        // epilogue: tanh + wv weighting, accumulate per-row partials
#pragma unroll
        for (int nf = 0; nf < 4; ++nf) {
            const int u = nb + nf * 16 + arow;  // D-layout: col = lane&15
            const float qv = qp2[b * UU + u];
            const float wvv = wv[u];
#pragma unroll
            for (int mf = 0; mf < 4; ++mf)
#pragma unroll
                for (int i = 0; i < 4; ++i) {
                    float h = acc[mf][nf][i] + qv;
                    float e = __expf(2.f * h);
                    float th = 1.f - 2.f / (e + 1.f);
                    rowsum[mf * 4 + i] = fmaf(th, wvv, rowsum[mf * 4 + i]);
                }
        }
    }

    // reduce across the 16 lanes holding different cols of the same rows
#pragma unroll
    for (int i = 0; i < 16; ++i) {
        float v = rowsum[i];
        v += __shfl_xor(v, 1);
        v += __shfl_xor(v, 2);
        v += __shfl_xor(v, 4);
        v += __shfl_xor(v, 8);
        rowsum[i] = v;
    }
    if ((lane & 15) == 0) {
        const int rg = lane >> 4;  // row-group 0..3
#pragma unroll
        for (int mf = 0; mf < 4; ++mf)
#pragma unroll
            for (int i = 0; i < 4; ++i)
                ssum[wid][mf * 16 + rg * 4 + i] = rowsum[mf * 4 + i];
    }
    __syncthreads();
    if (tid < MBLK) {
        float sc = ssum[0][tid] + ssum[1][tid] + ssum[2][tid] + ssum[3][tid] +
                   ssum[4][tid] + ssum[5][tid] + ssum[6][tid] + ssum[7][tid] + bv[0];
        score[b * SS + s0 + tid] = sc;
    }
}

// ---------------- K3a: softmax over S per batch ----------------
__global__ void softmax_kernel(const float* __restrict__ score, float* __restrict__ weights) {
    __shared__ float red[8];
    const int b = blockIdx.x;
    const int t = threadIdx.x;  // 256
    float local[8];
    float mx = -1e30f;
#pragma unroll
    for (int i = 0; i < 8; ++i) {
        local[i] = score[b * SS + i * 256 + t];
        mx = fmaxf(mx, local[i]);
    }
    for (int off = 1; off < 64; off <<= 1) mx = fmaxf(mx, __shfl_xor(mx, off));
    if ((t & 63) == 0) red[t >> 6] = mx;
    __syncthreads();
    const float m = fmaxf(fmaxf(red[0], red[1]), fmaxf(red[2], red[3]));
    float sum = 0.f;
#pragma unroll
    for (int i = 0; i < 8; ++i) {
        local[i] = __expf(local[i] - m);
        sum += local[i];
    }
    for (int off = 1; off < 64; off <<= 1) sum += __shfl_xor(sum, off);
    if ((t & 63) == 0) red[4 + (t >> 6)] = sum;
    __syncthreads();
    const float inv = 1.f / (red[4] + red[5] + red[6] + red[7]);
#pragma unroll
    for (int i = 0; i < 8; ++i) weights[b * SS + i * 256 + t] = local[i] * inv;
}

// ---------------- K3b: context[b,d] = sum_s w[b,s] * values[b,s,d], float4 loads ----
__global__ void context_kernel(const float* __restrict__ values, const float* __restrict__ weights,
                               float* __restrict__ ctx) {
    __shared__ f32x4 red[4][64];
    const int b = blockIdx.x;   // 32
    const int dc = blockIdx.y;  // 4 chunks of 256 cols
    const int t = threadIdx.x;  // 256
    const int l = t & 63;
    const int ph = t >> 6;      // 4 s-phases
    const int d = dc * 256 + l * 4;
    const float* vb = values + (size_t)b * SS * DD + d;
    const float* wb = weights + b * SS;
    f32x4 acc = {0.f, 0.f, 0.f, 0.f};
#pragma unroll 4
    for (int s = ph; s < SS; s += 4) {
        const float w = wb[s];
        float4 v = *reinterpret_cast<const float4*>(vb + (size_t)s * DD);
        acc[0] = fmaf(w, v.x, acc[0]);
        acc[1] = fmaf(w, v.y, acc[1]);
        acc[2] = fmaf(w, v.z, acc[2]);
        acc[3] = fmaf(w, v.w, acc[3]);
    }
    red[ph][l] = acc;
    __syncthreads();
    if (ph == 0) {
        f32x4 r = red[0][l];
        f32x4 r1 = red[1][l], r2 = red[2][l], r3 = red[3][l];
#pragma unroll
        for (int i = 0; i < 4; ++i) r[i] += r1[i] + r2[i] + r3[i];
        *reinterpret_cast<f32x4*>(ctx + (size_t)b * DD + d) = r;
    }
}

extern "C" void kernel_launch(void* const* d_in, const int* in_sizes, int n_in,
                              void* d_out, int out_size, void* d_ws, size_t ws_size,
                              hipStream_t stream) {
    const float* query  = (const float*)d_in[0];
    const float* values = (const float*)d_in[1];
    const float* w1     = (const float*)d_in[2];
    const float* b1     = (const float*)d_in[3];
    const float* w2     = (const float*)d_in[4];
    const float* b2     = (const float*)d_in[5];
    const float* wv     = (const float*)d_in[6];
    const float* bv     = (const float*)d_in[7];

    float* ctx     = (float*)d_out;                    // [B, D]
    float* weights = (float*)d_out + (size_t)BB * DD;  // [B, S, 1]

    float* qp2           = (float*)d_ws;                                  // 128 KB
    unsigned short* w2t  = (unsigned short*)((char*)d_ws + 131072);       // 2 MB
    float* score         = (float*)((char*)d_ws + 131072 + 2097152);      // 256 KB

    qproj_kernel<<<dim3(BB, UU / 256), 256, 0, stream>>>(query, w1, b1, b2, qp2);
    w2t_kernel<<<dim3(UU / 64, DD / 64), 256, 0, stream>>>(w2, w2t);
    score_kernel<<<dim3(BB * SS / MBLK), 512, 0, stream>>>(values, w2t, qp2, wv, bv, score);
    softmax_kernel<<<dim3(BB), 256, 0, stream>>>(score, weights);
    context_kernel<<<dim3(BB, 4), 256, 0, stream>>>(values, weights, ctx);
}

// Round 4
// 442.920 us; speedup vs baseline: 1.1864x; 1.0520x over previous
//
#include <hip/hip_runtime.h>
#include <hip/hip_bf16.h>

#define BB 32
#define SS 2048
#define DD 1024
#define UU 1024
#define MBLK 64
#define KPH 512  // K per LDS phase

typedef short bf16x8 __attribute__((ext_vector_type(8)));
typedef float f32x4 __attribute__((ext_vector_type(4)));

__device__ __forceinline__ unsigned short f2bf(float x) {
    union { float f; unsigned int u; } v; v.f = x;
    unsigned int r = v.u + 0x7fffu + ((v.u >> 16) & 1u);
    return (unsigned short)(r >> 16);
}

__device__ __forceinline__ f32x4 ntload4(const float* p) {
    return __builtin_nontemporal_load(reinterpret_cast<const f32x4*>(p));
}

// ---------------- K1a: q_proj = query@w1 + b1 + b2 ----------------
__global__ void qproj_kernel(const float* __restrict__ query, const float* __restrict__ w1,
                             const float* __restrict__ b1, const float* __restrict__ b2,
                             float* __restrict__ qp2) {
    __shared__ float qs[DD];
    const int b = blockIdx.x;   // 32
    const int uc = blockIdx.y;  // 4
    const int t = threadIdx.x;  // 256
    for (int i = t; i < DD; i += 256) qs[i] = query[b * DD + i];
    __syncthreads();
    const int u = uc * 256 + t;
    float acc = 0.f;
#pragma unroll 4
    for (int d = 0; d < DD; ++d) acc = fmaf(qs[d], w1[d * UU + u], acc);
    qp2[b * UU + u] = acc + b1[u] + b2[u];
}

// ---------------- K1b: w2t[u][d] = bf16(w2[d][u]) ----------------
__global__ void w2t_kernel(const float* __restrict__ w2, unsigned short* __restrict__ w2t) {
    __shared__ float tile[64][65];
    const int u0 = blockIdx.x * 64;
    const int d0 = blockIdx.y * 64;
    const int t = threadIdx.x;
    const int c = t & 63, rg = t >> 6;
#pragma unroll
    for (int rr = 0; rr < 16; ++rr) {
        int dl = rg * 16 + rr;
        tile[dl][c] = w2[(size_t)(d0 + dl) * UU + u0 + c];
    }
    __syncthreads();
#pragma unroll
    for (int rr = 0; rr < 16; ++rr) {
        int ul = rg * 16 + rr;
        w2t[(size_t)(u0 + ul) * DD + d0 + c] = f2bf(tile[c][ul]);
    }
}

// ---------------- K2: fused GEMM + tanh + wv-reduce -> score[b,s] ----------------
// 1024 threads = 16 waves (4/SIMD). Each wave owns ONE 64-col U-slice.
// K staged in 2 LDS phases of 512; acc persists across phases.
// values loads are non-temporal so w2t stays L2-resident.
__global__ __launch_bounds__(1024, 4)
void score_kernel(const float* __restrict__ values, const unsigned short* __restrict__ w2t,
                  const float* __restrict__ qp2, const float* __restrict__ wv,
                  const float* __restrict__ bv, float* __restrict__ score) {
    __shared__ __align__(16) unsigned short Vs[MBLK * KPH];  // 64 KB, XOR-swizzled
    __shared__ float ssum[16][MBLK];                          // 4 KB

    const int blk = blockIdx.x;       // 1024
    const int b = blk >> 5;
    const int s0 = (blk & 31) * MBLK;
    const int tid = threadIdx.x;
    const int lane = tid & 63;
    const int wid = tid >> 6;          // 0..15

    const int arow = lane & 15;        // frag row (A) / frag col (B,D)
    const int kgrp = (lane >> 4) * 8;  // k offset within frag
    const int nb = wid * 64;           // this wave's 64-col slice

    f32x4 acc[4][4];
#pragma unroll
    for (int mf = 0; mf < 4; ++mf)
#pragma unroll
        for (int nf = 0; nf < 4; ++nf) { f32x4 z = {0.f, 0.f, 0.f, 0.f}; acc[mf][nf] = z; }

    // staging indices: 1024 threads cover 64 rows x 512 cols
    const int srow = tid >> 4;         // 0..63
    const int sq = tid & 15;           // 16 threads per row

    for (int kp = 0; kp < 2; ++kp) {
        if (kp) __syncthreads();  // all reads of previous phase done
        {
            const float* src = values + ((size_t)b * SS + s0 + srow) * DD + kp * KPH;
#pragma unroll
            for (int jj = 0; jj < 4; ++jj) {
                const int e = sq * 8 + jj * 128;
                f32x4 x = ntload4(src + e);
                f32x4 y = ntload4(src + e + 4);
                bf16x8 pk;
                pk[0] = (short)f2bf(x[0]); pk[1] = (short)f2bf(x[1]);
                pk[2] = (short)f2bf(x[2]); pk[3] = (short)f2bf(x[3]);
                pk[4] = (short)f2bf(y[0]); pk[5] = (short)f2bf(y[1]);
                pk[6] = (short)f2bf(y[2]); pk[7] = (short)f2bf(y[3]);
                *reinterpret_cast<bf16x8*>(&Vs[srow * KPH + ((e) ^ ((srow & 7) << 3))]) = pk;
            }
        }
        __syncthreads();

        const unsigned short* wbase = w2t + (size_t)(nb + arow) * DD + kp * KPH + kgrp;
#pragma unroll 4
        for (int kk = 0; kk < KPH / 32; ++kk) {
            bf16x8 a[4], bf[4];
#pragma unroll
            for (int nf = 0; nf < 4; ++nf)
                bf[nf] = *reinterpret_cast<const bf16x8*>(wbase + (size_t)nf * 16 * DD + kk * 32);
#pragma unroll
            for (int mf = 0; mf < 4; ++mf) {
                int row = mf * 16 + arow;
                int k = kk * 32 + kgrp;
                a[mf] = *reinterpret_cast<const bf16x8*>(&Vs[row * KPH + (k ^ ((row & 7) << 3))]);
            }
#pragma unroll
            for (int mf = 0; mf < 4; ++mf)
#pragma unroll
                for (int nf = 0; nf < 4; ++nf)
                    acc[mf][nf] = __builtin_amdgcn_mfma_f32_16x16x32_bf16(a[mf], bf[nf], acc[mf][nf], 0, 0, 0);
        }
    }

    // epilogue: tanh + wv weighting, accumulate per-row partials
    float rowsum[16];
#pragma unroll
    for (int i = 0; i < 16; ++i) rowsum[i] = 0.f;
#pragma unroll
    for (int nf = 0; nf < 4; ++nf) {
        const int u = nb + nf * 16 + arow;
        const float qv = qp2[b * UU + u];
        const float wvv = wv[u];
#pragma unroll
        for (int mf = 0; mf < 4; ++mf)
#pragma unroll
            for (int i = 0; i < 4; ++i) {
                float h = acc[mf][nf][i] + qv;
                float e = __expf(2.f * h);
                float th = 1.f - 2.f / (e + 1.f);
                rowsum[mf * 4 + i] = fmaf(th, wvv, rowsum[mf * 4 + i]);
            }
    }

    // reduce across the 16 lanes holding different cols of the same rows
#pragma unroll
    for (int i = 0; i < 16; ++i) {
        float v = rowsum[i];
        v += __shfl_xor(v, 1);
        v += __shfl_xor(v, 2);
        v += __shfl_xor(v, 4);
        v += __shfl_xor(v, 8);
        rowsum[i] = v;
    }
    if ((lane & 15) == 0) {
        const int rg = lane >> 4;
#pragma unroll
        for (int mf = 0; mf < 4; ++mf)
#pragma unroll
            for (int i = 0; i < 4; ++i)
                ssum[wid][mf * 16 + rg * 4 + i] = rowsum[mf * 4 + i];
    }
    __syncthreads();
    if (tid < MBLK) {
        float sc = bv[0];
#pragma unroll
        for (int w = 0; w < 16; ++w) sc += ssum[w][tid];
        score[b * SS + s0 + tid] = sc;
    }
}

// ---------------- K3a: softmax over S per batch ----------------
__global__ void softmax_kernel(const float* __restrict__ score, float* __restrict__ weights) {
    __shared__ float red[8];
    const int b = blockIdx.x;
    const int t = threadIdx.x;  // 256
    float local[8];
    float mx = -1e30f;
#pragma unroll
    for (int i = 0; i < 8; ++i) {
        local[i] = score[b * SS + i * 256 + t];
        mx = fmaxf(mx, local[i]);
    }
    for (int off = 1; off < 64; off <<= 1) mx = fmaxf(mx, __shfl_xor(mx, off));
    if ((t & 63) == 0) red[t >> 6] = mx;
    __syncthreads();
    const float m = fmaxf(fmaxf(red[0], red[1]), fmaxf(red[2], red[3]));
    float sum = 0.f;
#pragma unroll
    for (int i = 0; i < 8; ++i) {
        local[i] = __expf(local[i] - m);
        sum += local[i];
    }
    for (int off = 1; off < 64; off <<= 1) sum += __shfl_xor(sum, off);
    if ((t & 63) == 0) red[4 + (t >> 6)] = sum;
    __syncthreads();
    const float inv = 1.f / (red[4] + red[5] + red[6] + red[7]);
#pragma unroll
    for (int i = 0; i < 8; ++i) weights[b * SS + i * 256 + t] = local[i] * inv;
}

// ---------------- K3b: context[b,d] = sum_s w[b,s] * values[b,s,d] ----------------
// grid (32, 16): 64-col chunks, 2 blocks/CU, weights staged in LDS, nt loads.
__global__ void context_kernel(const float* __restrict__ values, const float* __restrict__ weights,
                               float* __restrict__ ctx) {
    __shared__ float ws[SS];          // 8 KB
    __shared__ f32x4 red[16][16];     // 4 KB
    const int b = blockIdx.x;   // 32
    const int dc = blockIdx.y;  // 16
    const int t = threadIdx.x;  // 256
    for (int i = t; i < SS; i += 256) ws[i] = weights[b * SS + i];
    __syncthreads();
    const int dt = t & 15;      // 16 d-threads (64 cols)
    const int ph = t >> 4;      // 16 s-phases
    const int d = dc * 64 + dt * 4;
    const float* vb = values + (size_t)b * SS * DD + d;
    f32x4 acc = {0.f, 0.f, 0.f, 0.f};
#pragma unroll 8
    for (int s = ph; s < SS; s += 16) {
        const float w = ws[s];
        f32x4 v = ntload4(vb + (size_t)s * DD);
        acc[0] = fmaf(w, v[0], acc[0]);
        acc[1] = fmaf(w, v[1], acc[1]);
        acc[2] = fmaf(w, v[2], acc[2]);
        acc[3] = fmaf(w, v[3], acc[3]);
    }
    red[ph][dt] = acc;
    __syncthreads();
    if (t < 16) {
        f32x4 r = red[0][t];
#pragma unroll
        for (int w = 1; w < 16; ++w) {
            f32x4 x = red[w][t];
#pragma unroll
            for (int i = 0; i < 4; ++i) r[i] += x[i];
        }
        *reinterpret_cast<f32x4*>(ctx + (size_t)b * DD + dc * 64 + t * 4) = r;
    }
}

extern "C" void kernel_launch(void* const* d_in, const int* in_sizes, int n_in,
                              void* d_out, int out_size, void* d_ws, size_t ws_size,
                              hipStream_t stream) {
    const float* query  = (const float*)d_in[0];
    const float* values = (const float*)d_in[1];
    const float* w1     = (const float*)d_in[2];
    const float* b1     = (const float*)d_in[3];
    const float* w2     = (const float*)d_in[4];
    const float* b2     = (const float*)d_in[5];
    const float* wv     = (const float*)d_in[6];
    const float* bv     = (const float*)d_in[7];

    float* ctx     = (float*)d_out;                    // [B, D]
    float* weights = (float*)d_out + (size_t)BB * DD;  // [B, S, 1]

    float* qp2           = (float*)d_ws;                                  // 128 KB
    unsigned short* w2t  = (unsigned short*)((char*)d_ws + 131072);       // 2 MB
    float* score         = (float*)((char*)d_ws + 131072 + 2097152);      // 256 KB

    qproj_kernel<<<dim3(BB, UU / 256), 256, 0, stream>>>(query, w1, b1, b2, qp2);
    w2t_kernel<<<dim3(UU / 64, DD / 64), 256, 0, stream>>>(w2, w2t);
    score_kernel<<<dim3(BB * SS / MBLK), 1024, 0, stream>>>(values, w2t, qp2, wv, bv, score);
    softmax_kernel<<<dim3(BB), 256, 0, stream>>>(score, weights);
    context_kernel<<<dim3(BB, 16), 256, 0, stream>>>(values, weights, ctx);
}